// Round 2
// baseline (599.220 us; speedup 1.0000x reference)
//
#include <hip/hip_runtime.h>
#include <cstdint>

#define T_SEQ 40
#define NB    16384
#define NH    128
#define NROWS 136          // 128 recurrent rows + 8 input rows
#define ROWD  129          // dword stride per row: staging writes (lane-stride 129 -> bank-stride 1)
                           // and spike reads (lane-stride 1, two b32 phases) both conflict-free
#define WPB   16           // waves (batch rows) per block
#define NTHR  (WPB * 64)

// ---- wave-wide sum of two floats via DPP (VALU pipe; keeps DS pipe free) ----
template <int C>
__device__ __forceinline__ float dppstep(float v) {
  int t = __builtin_amdgcn_update_dpp(0, __float_as_int(v), C, 0xF, 0xF, true);
  return v + __int_as_float(t);
}
__device__ __forceinline__ void wave_sum2(float &a, float &b) {
  a = dppstep<0x111>(a); b = dppstep<0x111>(b);   // row_shr:1
  a = dppstep<0x112>(a); b = dppstep<0x112>(b);   // row_shr:2
  a = dppstep<0x114>(a); b = dppstep<0x114>(b);   // row_shr:4
  a = dppstep<0x118>(a); b = dppstep<0x118>(b);   // row_shr:8  -> lane15/31/47/63 hold row sums
  a = dppstep<0x142>(a); b = dppstep<0x142>(b);   // row_bcast15
  a = dppstep<0x143>(a); b = dppstep<0x143>(b);   // row_bcast31 -> lane63 holds total
  a = __int_as_float(__builtin_amdgcn_readlane(__float_as_int(a), 63));
  b = __int_as_float(__builtin_amdgcn_readlane(__float_as_int(b), 63));
}

// scalar-uniform spike iterator. bE bit l -> recurrent row l; bO bit l -> row 64+l;
// bI bit k -> input row 128+k. Yields LDS dword offset of the weight row, or -1.
#define NEXT_OFF(dst) do {                                                       \
    if (mE)      { int l_ = __builtin_ctzll(mE); mE &= mE - 1; dst = l_ * ROWD; }         \
    else if (mO) { int l_ = __builtin_ctzll(mO); mO &= mO - 1; dst = (64 + l_) * ROWD; }  \
    else if (mI) { int l_ = __builtin_ctzll(mI); mI &= mI - 1; dst = (128 + l_) * ROWD; } \
    else dst = -1;                                                               \
  } while (0)

__global__ __launch_bounds__(NTHR, 8)
void Policy_22033182228693_kernel(const float* __restrict__ x,
                                  const float* __restrict__ w_in,
                                  const float* __restrict__ w_rec,
                                  const float* __restrict__ w_out,
                                  const float* __restrict__ dmask,
                                  float* __restrict__ out)
{
  __shared__ float W[NROWS * ROWD];   // 70,176 B -> 2 blocks/CU (32 waves = full occupancy)

  const int tid = threadIdx.x;
  // Stage w_rec transposed: W[j][h] = w_rec[h][j]. Global reads coalesced;
  // LDS writes: consecutive lanes -> j consecutive -> addr stride ROWD=129 -> bank stride 1 (free).
  for (int e = tid; e < NH * NH; e += NTHR) {
    int h = e >> 7, j = e & 127;
    W[j * ROWD + h] = w_rec[e];
  }
  // Stage w_in transposed into rows 128..135: W[128+k][h] = w_in[h][k]
  for (int e = tid; e < NH * 8; e += NTHR) {
    int h = e >> 3, k = e & 7;
    W[(128 + k) * ROWD + h] = w_in[e];
  }
  __syncthreads();   // only barrier in the kernel

  const int wave = tid >> 6;
  const int lane = tid & 63;
  const int b    = blockIdx.x * WPB + wave;   // one batch row per wave
  // lane owns neurons h = lane and h = lane + 64

  // Encoder constant current: lanes 0..3 -> relu(50*x[k]), lanes 4..7 -> relu(-50*x[k])
  float xv = x[(size_t)b * 4 + (lane & 3)];
  float cc = fmaxf(0.f, ((lane & 4) ? -50.f : 50.f) * xv);
  if (lane >= 8) cc = 0.f;

  // Readout weights for this lane's two neurons (w_out shape (2,128) row-major)
  const float wo00 = w_out[lane];        // w_out[0][lane]
  const float wo01 = w_out[lane + 64];   // w_out[0][lane+64]
  const float wo10 = w_out[128 + lane];  // w_out[1][lane]
  const float wo11 = w_out[192 + lane];  // w_out[1][lane+64]

  // Dropout mask stream: two b32 per lane per step (dwords lane, lane+64), 2-deep prefetch
  const float* gm = dmask + (size_t)b * NH + lane;
  const size_t TS = (size_t)NB * NH;
  float mc0 = gm[0],  mc1 = gm[64];
  float mn0 = gm[TS], mn1 = gm[TS + 64];

  float ve = 0.f;                                  // encoder membrane
  float v0 = 0.f, v1 = 0.f, i0 = 0.f, i1 = 0.f;    // hidden LIF state (h=lane, h=lane+64)
  float io0 = 0.f, io1 = 0.f, vo0 = 0.f, vo1 = 0.f;
  float m0 = -3.0e38f, m1 = -3.0e38f;
  uint64_t bE = 0, bO = 0;                         // previous-step spike ballots (carry z)

#pragma unroll 1
  for (int t = 0; t < T_SEQ; ++t) {
    // ---- encoder advance (produces xs[t]) ----
    ve += 0.1f * (cc - ve);
    bool zi = ve > 1.0f;
    if (zi) ve = 0.f;
    uint64_t bI = __ballot((int)zi);               // bits 0..7 = input channels

    // ---- hidden membrane (uses old i) ----
    float vd0 = v0 + 0.1f * (i0 - v0);
    float vd1 = v1 + 0.1f * (i1 - v1);
    bool z0 = vd0 > 1.0f, z1 = vd1 > 1.0f;
    v0 = z0 ? 0.f : vd0;
    v1 = z1 ? 0.f : vd1;

    // ---- synaptic current: decay + sparse column gather (prev z, current input) ----
    float a0 = 0.8f * i0, a1 = 0.8f * i1;
    {
      uint64_t mE = bE, mO = bO, mI = bI;
      int oA;
      NEXT_OFF(oA);
      if (oA >= 0) {                               // depth-1 SW pipeline on ds_read2_b32
        float wA0 = W[oA + lane];
        float wA1 = W[oA + lane + 64];
        int oB; NEXT_OFF(oB);
        while (oB >= 0) {
          float wB0 = W[oB + lane];
          float wB1 = W[oB + lane + 64];
          a0 += wA0; a1 += wA1;
          wA0 = wB0; wA1 = wB1;
          NEXT_OFF(oB);
        }
        a0 += wA0; a1 += wA1;
      }
    }
    i0 = a0; i1 = a1;

    // ballots for next step's recurrent input
    bE = __ballot((int)z0);
    bO = __ballot((int)z1);

    // ---- dropout + readout ----
    float mt0 = mc0, mt1 = mc1;
    mc0 = mn0; mc1 = mn1;
    int tp = (t + 2 < T_SEQ) ? t + 2 : T_SEQ - 1;
    mn0 = gm[(size_t)tp * TS];
    mn1 = gm[(size_t)tp * TS + 64];

    float zd0 = z0 ? mt0 : 0.f;
    float zd1 = z1 ? mt1 : 0.f;
    float u0 = zd0 * wo00 + zd1 * wo01;
    float u1 = zd0 * wo10 + zd1 * wo11;
    if (bE | bO) {
      wave_sum2(u0, u1);
    } else {
      u0 = 0.f; u1 = 0.f;
    }

    vo0 += 0.1f * (io0 - vo0);                     // vo_new uses old io
    vo1 += 0.1f * (io1 - vo1);
    io0 = 0.8f * io0 + u0;
    io1 = 0.8f * io1 + u1;
    m0 = fmaxf(m0, vo0);
    m1 = fmaxf(m1, vo1);
  }

  if (lane == 0) {
    float mx = fmaxf(m0, m1);
    float e0 = expf(m0 - mx), e1 = expf(m1 - mx);
    float inv = 1.f / (e0 + e1);
    ((float2*)out)[b] = make_float2(e0 * inv, e1 * inv);
  }
}

extern "C" void kernel_launch(void* const* d_in, const int* in_sizes, int n_in,
                              void* d_out, int out_size, void* d_ws, size_t ws_size,
                              hipStream_t stream) {
  const float* x     = (const float*)d_in[0];
  const float* w_in  = (const float*)d_in[1];
  const float* w_rec = (const float*)d_in[2];
  const float* w_out = (const float*)d_in[3];
  const float* dmask = (const float*)d_in[4];
  float* out = (float*)d_out;

  dim3 grid(NB / WPB);   // 1024 blocks
  dim3 block(NTHR);      // 1024 threads = 16 waves = 16 batch rows
  hipLaunchKernelGGL(Policy_22033182228693_kernel, grid, block, 0, stream,
                     x, w_in, w_rec, w_out, dmask, out);
}

// Round 3
// 502.760 us; speedup vs baseline: 1.1919x; 1.1919x over previous
//
#include <hip/hip_runtime.h>
#include <cstdint>

#define T_SEQ 40
#define NB    16384
#define NH    128
#define NROWS 136          // 128 recurrent rows + 8 input rows
#define ROWD  129          // staging writes lane-stride 129 -> bank-stride 1; reads lane-stride 1: conflict-free
#define WPB   16           // waves (batch rows) per block
#define NTHR  (WPB * 64)

// ---- wave-wide sum of two floats via DPP (VALU pipe; keeps DS pipe free) ----
template <int C>
__device__ __forceinline__ float dppstep(float v) {
  int t = __builtin_amdgcn_update_dpp(0, __float_as_int(v), C, 0xF, 0xF, true);
  return v + __int_as_float(t);
}
__device__ __forceinline__ void wave_sum2(float &a, float &b) {
  a = dppstep<0x111>(a); b = dppstep<0x111>(b);   // row_shr:1
  a = dppstep<0x112>(a); b = dppstep<0x112>(b);   // row_shr:2
  a = dppstep<0x114>(a); b = dppstep<0x114>(b);   // row_shr:4
  a = dppstep<0x118>(a); b = dppstep<0x118>(b);   // row_shr:8
  a = dppstep<0x142>(a); b = dppstep<0x142>(b);   // row_bcast15
  a = dppstep<0x143>(a); b = dppstep<0x143>(b);   // row_bcast31 -> lane63 total
  a = __int_as_float(__builtin_amdgcn_readlane(__float_as_int(a), 63));
  b = __int_as_float(__builtin_amdgcn_readlane(__float_as_int(b), 63));
}

__global__ __launch_bounds__(NTHR, 8)
void Policy_22033182228693_kernel(const float* __restrict__ x,
                                  const float* __restrict__ w_in,
                                  const float* __restrict__ w_rec,
                                  const float* __restrict__ w_out,
                                  const float* __restrict__ dmask,
                                  float* __restrict__ out)
{
  __shared__ float W[NROWS * ROWD];   // 70,176 B -> 2 blocks/CU = 32 waves (max)

  const int tid = threadIdx.x;
  for (int e = tid; e < NH * NH; e += NTHR) {        // W[j][h] = w_rec[h][j]
    int h = e >> 7, j = e & 127;
    W[j * ROWD + h] = w_rec[e];
  }
  for (int e = tid; e < NH * 8; e += NTHR) {         // W[128+k][h] = w_in[h][k]
    int h = e >> 3, k = e & 7;
    W[(128 + k) * ROWD + h] = w_in[e];
  }
  __syncthreads();   // only barrier

  const int wave = tid >> 6;
  const int lane = tid & 63;
  const int b    = blockIdx.x * WPB + wave;   // one batch row per wave; lane owns h=lane, h=lane+64

  // Encoder constant current
  float xv = x[(size_t)b * 4 + (lane & 3)];
  float cc = fmaxf(0.f, ((lane & 4) ? -50.f : 50.f) * xv);
  if (lane >= 8) cc = 0.f;

  // Channels with cc > 10 spike EVERY step (0.1*cc > 1 right after reset).
  // Precompute their summed w_in rows once; exclude them from the per-step encoder.
  bool always = cc > 10.f;
  uint64_t aM = __ballot((int)always);
  if (always) cc = 0.f;                       // never spikes in the loop
  float c0 = 0.f, c1 = 0.f;
  {
    uint64_t m = aM;
    while (m) {
      int k = __builtin_ctzll(m); m &= m - 1;
      int o = (128 + k) * ROWD;
      c0 += W[o + lane]; c1 += W[o + lane + 64];
    }
  }

  // Readout weights (w_out shape (2,128))
  const float wo00 = w_out[lane];
  const float wo01 = w_out[lane + 64];
  const float wo10 = w_out[128 + lane];
  const float wo11 = w_out[192 + lane];

  // Dropout mask: scalar step offsets (TS = 2^21 dwords) + lane vaddr -> saddr-form loads
  const float* gmu = dmask + (size_t)b * NH;  // wave-uniform
  const size_t TS = (size_t)NB * NH;          // 2^21
  float mc0 = gmu[lane],      mc1 = gmu[lane + 64];
  float mn0 = gmu[TS + lane], mn1 = gmu[TS + lane + 64];

  float ve = 0.f;
  float v0 = 0.f, v1 = 0.f, i0 = 0.f, i1 = 0.f;
  float io0 = 0.f, io1 = 0.f, vo0 = 0.f, vo1 = 0.f;
  float m0 = -3.0e38f, m1 = -3.0e38f;
  uint64_t bE = 0, bO = 0;

#pragma unroll 1
  for (int t = 0; t < T_SEQ; ++t) {
    // encoder (slow channels only)
    ve += 0.1f * (cc - ve);
    bool zi = ve > 1.0f;
    if (zi) ve = 0.f;
    uint64_t bI = __ballot((int)zi);

    // hidden membrane (uses old i)
    float vd0 = v0 + 0.1f * (i0 - v0);
    float vd1 = v1 + 0.1f * (i1 - v1);
    bool z0 = vd0 > 1.0f, z1 = vd1 > 1.0f;
    v0 = z0 ? 0.f : vd0;
    v1 = z1 ? 0.f : vd1;

    // synaptic current: decay + sparse gather (prev z), fused dual-mask loop
    float a0 = 0.8f * i0, a1 = 0.8f * i1;
    {
      uint64_t mA = bE, mB = bO;
      int nA = __popcll(mA), nB = __popcll(mB);
      int nP = nA < nB ? nA : nB;
      if (nP > 0) {
        int oA = __builtin_ctzll(mA) * ROWD;        mA &= mA - 1;
        int oB = (64 + __builtin_ctzll(mB)) * ROWD; mB &= mB - 1;
        float p0 = W[oA + lane], p1 = W[oA + lane + 64];
        float q0 = W[oB + lane], q1 = W[oB + lane + 64];
#pragma unroll 2
        for (int k = 1; k < nP; ++k) {
          int o2 = __builtin_ctzll(mA) * ROWD;        mA &= mA - 1;
          int o3 = (64 + __builtin_ctzll(mB)) * ROWD; mB &= mB - 1;
          float r0 = W[o2 + lane], r1 = W[o2 + lane + 64];
          float s0 = W[o3 + lane], s1 = W[o3 + lane + 64];
          a0 += p0 + q0; a1 += p1 + q1;
          p0 = r0; p1 = r1; q0 = s0; q1 = s1;
        }
        a0 += p0 + q0; a1 += p1 + q1;
      }
      // drain: at most one of mA/mB nonzero
      uint64_t mR; int rb;
      if (mA) { mR = mA; rb = 0; } else { mR = mB; rb = 64; }
      while (mR) {
        int o = (rb + __builtin_ctzll(mR)) * ROWD; mR &= mR - 1;
        a0 += W[o + lane]; a1 += W[o + lane + 64];
      }
      // slow input channels (rare, ~0.65/step)
      while (bI) {
        int o = (128 + __builtin_ctzll(bI)) * ROWD; bI &= bI - 1;
        a0 += W[o + lane]; a1 += W[o + lane + 64];
      }
      a0 += c0; a1 += c1;    // always-on input contribution
    }
    i0 = a0; i1 = a1;

    bE = __ballot((int)z0);
    bO = __ballot((int)z1);

    // dropout + readout
    float mt0 = mc0, mt1 = mc1;
    mc0 = mn0; mc1 = mn1;
    int tp = (t + 2 < T_SEQ) ? t + 2 : T_SEQ - 1;
    size_t so = (size_t)tp * TS;
    mn0 = gmu[so + lane];
    mn1 = gmu[so + lane + 64];

    float zd0 = z0 ? mt0 : 0.f;
    float zd1 = z1 ? mt1 : 0.f;
    float u0 = zd0 * wo00 + zd1 * wo01;
    float u1 = zd0 * wo10 + zd1 * wo11;
    if (bE | bO) {
      wave_sum2(u0, u1);
    } else {
      u0 = 0.f; u1 = 0.f;
    }

    vo0 += 0.1f * (io0 - vo0);
    vo1 += 0.1f * (io1 - vo1);
    io0 = 0.8f * io0 + u0;
    io1 = 0.8f * io1 + u1;
    m0 = fmaxf(m0, vo0);
    m1 = fmaxf(m1, vo1);
  }

  if (lane == 0) {
    float mx = fmaxf(m0, m1);
    float e0 = expf(m0 - mx), e1 = expf(m1 - mx);
    float inv = 1.f / (e0 + e1);
    ((float2*)out)[b] = make_float2(e0 * inv, e1 * inv);
  }
}

extern "C" void kernel_launch(void* const* d_in, const int* in_sizes, int n_in,
                              void* d_out, int out_size, void* d_ws, size_t ws_size,
                              hipStream_t stream) {
  const float* x     = (const float*)d_in[0];
  const float* w_in  = (const float*)d_in[1];
  const float* w_rec = (const float*)d_in[2];
  const float* w_out = (const float*)d_in[3];
  const float* dmask = (const float*)d_in[4];
  float* out = (float*)d_out;

  dim3 grid(NB / WPB);   // 1024 blocks
  dim3 block(NTHR);      // 1024 threads = 16 waves = 16 batch rows
  hipLaunchKernelGGL(Policy_22033182228693_kernel, grid, block, 0, stream,
                     x, w_in, w_rec, w_out, dmask, out);
}